// Round 6
// baseline (99.803 us; speedup 1.0000x reference)
//
#include <hip/hip_runtime.h>
#include <math.h>

#define BB 256      // batch
#define CC 1024     // channels
#define CC4 (CC/4)  // row length in float4
#define MARGIN 0.5f

// ws layout (floats): mcsq[256*1024] | S[256*256] | IDS[256*256] | MD[256*256] | acc | cnt

// ---------------------------------------------------------------------------
// K1: mcsq[i,c] = m_counts[i,c]^2. One wave per row; ballot partner select.
// Also zeroes S/IDS/MD (12 stores/lane over 3*64K floats) and acc/cnt.
// ---------------------------------------------------------------------------
__global__ __launch_bounds__(64) void mcsq_kernel(
    const float* __restrict__ x, const int* __restrict__ targets,
    const int* __restrict__ subs, const int* __restrict__ m_count_p,
    float* __restrict__ mcsq, float* __restrict__ zbase,
    float* __restrict__ acc, unsigned int* __restrict__ cnt_g)
{
    const int i = blockIdx.x;
    const int lane = threadIdx.x;
    if (i == 0 && lane == 0) { *acc = 0.f; *cnt_g = 0u; }
    {
        const int g = i * 64 + lane;            // 0..16383
        #pragma unroll
        for (int t = 0; t < 12; ++t) zbase[g + 16384 * t] = 0.f;  // 196608 = 3*65536
    }
    const int ti = targets[i], si = subs[i];
    int mc = *m_count_p;
    if (mc > 8) mc = 8;

    unsigned long long masks[4];
    #pragma unroll
    for (int q = 0; q < 4; ++q) {
        const int j = q * 64 + lane;
        masks[q] = __ballot(targets[j] == ti && subs[j] == si);
    }
    int idx[8];
    int cnt = 0;
    for (int q = 0; q < 4 && cnt < mc; ++q) {
        unsigned long long m = masks[q];
        while (m && cnt < mc) {
            const int b = __ffsll(m) - 1;
            idx[cnt++] = q * 64 + b;
            m &= m - 1;
        }
    }
    for (int q = 0; q < 4 && cnt < mc; ++q) {   // stable-argsort padding
        unsigned long long m = ~masks[q];
        while (m && cnt < mc) {
            const int b = __ffsll(m) - 1;
            idx[cnt++] = q * 64 + b;
            m &= m - 1;
        }
    }

    const float4* x4 = (const float4*)x;
    float4 xi[4];
    #pragma unroll
    for (int t = 0; t < 4; ++t) xi[t] = x4[(long)i * CC4 + lane + 64 * t];

    float4 c4[4];
    #pragma unroll
    for (int t = 0; t < 4; ++t) c4[t] = make_float4(0.f, 0.f, 0.f, 0.f);

    for (int k = 0; k < cnt; ++k) {
        float4 ad[4];
        float s = 0.f;
        #pragma unroll
        for (int t = 0; t < 4; ++t) {
            const float4 xj = x4[(long)idx[k] * CC4 + lane + 64 * t];
            ad[t].x = fabsf(xi[t].x - xj.x);
            ad[t].y = fabsf(xi[t].y - xj.y);
            ad[t].z = fabsf(xi[t].z - xj.z);
            ad[t].w = fabsf(xi[t].w - xj.w);
            s += ad[t].x + ad[t].y + ad[t].z + ad[t].w;
        }
        #pragma unroll
        for (int off = 32; off > 0; off >>= 1) s += __shfl_xor(s, off, 64);
        const float thr = s * (MARGIN / CC);   // 0.5 * mean
        #pragma unroll
        for (int t = 0; t < 4; ++t) {
            c4[t].x += (ad[t].x < thr) ? 1.f : 0.f;
            c4[t].y += (ad[t].y < thr) ? 1.f : 0.f;
            c4[t].z += (ad[t].z < thr) ? 1.f : 0.f;
            c4[t].w += (ad[t].w < thr) ? 1.f : 0.f;
        }
    }
    float4* m4 = (float4*)mcsq;
    #pragma unroll
    for (int t = 0; t < 4; ++t) {
        float4 o;
        o.x = c4[t].x * c4[t].x;
        o.y = c4[t].y * c4[t].y;
        o.z = c4[t].z * c4[t].z;
        o.w = c4[t].w * c4[t].w;
        m4[(long)i * CC4 + lane + 64 * t] = o;
    }
}

// ---------------------------------------------------------------------------
// K2 (pass1): L1-distance matrix S[i][j] = sum_c |x_i[c]-x_j[c]|.
// Block = 32i x 32j x 128c tile; lane owns a 2x2 pair block; zero cross-lane
// ops; atomicAdd partials into S. Grid 8*8*8 = 512 blocks.
// LDS row stride 129 -> all 4 read patterns bank-conflict-free.
// ---------------------------------------------------------------------------
__global__ __launch_bounds__(256) void pass1_kernel(
    const float* __restrict__ x, float* __restrict__ S)
{
    __shared__ float xs[64 * 129];
    const int b  = blockIdx.x;
    const int cc = b & 7;          // c-chunk of 128
    const int jt = (b >> 3) & 7;
    const int it = b >> 6;
    const int l  = threadIdx.x;

    const float4* x4 = (const float4*)x;
    #pragma unroll
    for (int k = 0; k < 8; ++k) {
        const int idx = l + 256 * k;       // 0..2047
        const int row = idx >> 5;          // 0..63
        const int c4  = idx & 31;
        const int grow = (row < 32) ? (it * 32 + row) : (jt * 32 + row - 32);
        const float4 v = x4[grow * CC4 + cc * 32 + c4];
        float* dst = &xs[row * 129 + c4 * 4];
        dst[0] = v.x; dst[1] = v.y; dst[2] = v.z; dst[3] = v.w;
    }
    __syncthreads();

    const int li = l >> 4, lj = l & 15;
    const float* pi0 = &xs[(2 * li) * 129];
    const float* pi1 = &xs[(2 * li + 1) * 129];
    const float* pj0 = &xs[(32 + 2 * lj) * 129];
    const float* pj1 = &xs[(32 + 2 * lj + 1) * 129];
    float s00 = 0.f, s01 = 0.f, s10 = 0.f, s11 = 0.f;
    #pragma unroll 8
    for (int c = 0; c < 128; ++c) {
        const float a0 = pi0[c], a1 = pi1[c], b0 = pj0[c], b1 = pj1[c];
        s00 += fabsf(a0 - b0); s01 += fabsf(a0 - b1);
        s10 += fabsf(a1 - b0); s11 += fabsf(a1 - b1);
    }
    const int gi0 = it * 32 + 2 * li, gj0 = jt * 32 + 2 * lj;
    atomicAdd(&S[gi0 * BB + gj0],           s00);
    atomicAdd(&S[gi0 * BB + gj0 + 1],       s01);
    atomicAdd(&S[(gi0 + 1) * BB + gj0],     s10);
    atomicAdd(&S[(gi0 + 1) * BB + gj0 + 1], s11);
}

// ---------------------------------------------------------------------------
// K3 (pass2): IDS[i][j] = sum_c d^2 * [|d| < thr(i,j)], MD[i][j] = sum_c
// d^2 * mcsq_i[c] * mcsq_j[c], with thr = S[i][j] * (0.5/1024).
// Block = 32i x 32j x 64c; stages x and mcsq; lane owns 2x2 pairs.
// Grid 8*8*16 = 1024 blocks. LDS stride 65 -> conflict-free reads.
// ---------------------------------------------------------------------------
__global__ __launch_bounds__(256) void pass2_kernel(
    const float* __restrict__ x, const float* __restrict__ mcsq,
    const float* __restrict__ S,
    float* __restrict__ IDS, float* __restrict__ MD)
{
    __shared__ float xs[64 * 65];
    __shared__ float ms[64 * 65];
    const int b  = blockIdx.x;
    const int cc = b & 15;         // c-chunk of 64
    const int jt = (b >> 4) & 7;
    const int it = b >> 7;
    const int l  = threadIdx.x;

    const float4* x4 = (const float4*)x;
    const float4* m4 = (const float4*)mcsq;
    #pragma unroll
    for (int k = 0; k < 4; ++k) {
        const int idx = l + 256 * k;       // 0..1023
        const int row = idx >> 4;          // 0..63
        const int c4  = idx & 15;
        const int grow = (row < 32) ? (it * 32 + row) : (jt * 32 + row - 32);
        const float4 v = x4[grow * CC4 + cc * 16 + c4];
        const float4 w = m4[grow * CC4 + cc * 16 + c4];
        float* dx = &xs[row * 65 + c4 * 4];
        dx[0] = v.x; dx[1] = v.y; dx[2] = v.z; dx[3] = v.w;
        float* dm = &ms[row * 65 + c4 * 4];
        dm[0] = w.x; dm[1] = w.y; dm[2] = w.z; dm[3] = w.w;
    }

    const int li = l >> 4, lj = l & 15;
    const int gi0 = it * 32 + 2 * li, gj0 = jt * 32 + 2 * lj;
    const float t00 = S[gi0 * BB + gj0]           * (MARGIN / CC);
    const float t01 = S[gi0 * BB + gj0 + 1]       * (MARGIN / CC);
    const float t10 = S[(gi0 + 1) * BB + gj0]     * (MARGIN / CC);
    const float t11 = S[(gi0 + 1) * BB + gj0 + 1] * (MARGIN / CC);
    __syncthreads();

    const float* pi0 = &xs[(2 * li) * 65];
    const float* pi1 = &xs[(2 * li + 1) * 65];
    const float* pj0 = &xs[(32 + 2 * lj) * 65];
    const float* pj1 = &xs[(32 + 2 * lj + 1) * 65];
    const float* qi0 = &ms[(2 * li) * 65];
    const float* qi1 = &ms[(2 * li + 1) * 65];
    const float* qj0 = &ms[(32 + 2 * lj) * 65];
    const float* qj1 = &ms[(32 + 2 * lj + 1) * 65];

    float i00 = 0.f, i01 = 0.f, i10 = 0.f, i11 = 0.f;
    float m00 = 0.f, m01 = 0.f, m10 = 0.f, m11 = 0.f;
    #pragma unroll 4
    for (int c = 0; c < 64; ++c) {
        const float a0 = pi0[c], a1 = pi1[c], b0 = pj0[c], b1 = pj1[c];
        const float wa0 = qi0[c], wa1 = qi1[c], wb0 = qj0[c], wb1 = qj1[c];
        float d, q;
        d = a0 - b0; q = d * d; i00 += (fabsf(d) < t00) ? q : 0.f; m00 += q * wa0 * wb0;
        d = a0 - b1; q = d * d; i01 += (fabsf(d) < t01) ? q : 0.f; m01 += q * wa0 * wb1;
        d = a1 - b0; q = d * d; i10 += (fabsf(d) < t10) ? q : 0.f; m10 += q * wa1 * wb0;
        d = a1 - b1; q = d * d; i11 += (fabsf(d) < t11) ? q : 0.f; m11 += q * wa1 * wb1;
    }
    atomicAdd(&IDS[gi0 * BB + gj0],           i00);
    atomicAdd(&IDS[gi0 * BB + gj0 + 1],       i01);
    atomicAdd(&IDS[(gi0 + 1) * BB + gj0],     i10);
    atomicAdd(&IDS[(gi0 + 1) * BB + gj0 + 1], i11);
    atomicAdd(&MD[gi0 * BB + gj0],            m00);
    atomicAdd(&MD[gi0 * BB + gj0 + 1],        m01);
    atomicAdd(&MD[(gi0 + 1) * BB + gj0],      m10);
    atomicAdd(&MD[(gi0 + 1) * BB + gj0 + 1],  m11);
}

// ---------------------------------------------------------------------------
// K4: final. One wave per row i: float4 loads of MD/IDS row, one max/min
// butterfly, atomic mean accumulation; last block publishes to out.
// ---------------------------------------------------------------------------
__global__ __launch_bounds__(64) void final_kernel(
    const float* __restrict__ IDS, const float* __restrict__ MD,
    const int* __restrict__ targets,
    float* __restrict__ acc, unsigned int* __restrict__ cnt_g,
    float* __restrict__ out)
{
    const int i = blockIdx.x;
    const int lane = threadIdx.x;
    const int ti = targets[i];
    const float4 mdv = ((const float4*)(MD  + i * BB))[lane];
    const float4 idv = ((const float4*)(IDS + i * BB))[lane];
    const int4   tjv = ((const int4*)targets)[lane];

    float mx, mn;
    mx =            sqrtf(fmaxf(mdv.x, 1e-12f));
    mx = fmaxf(mx,  sqrtf(fmaxf(mdv.y, 1e-12f)));
    mx = fmaxf(mx,  sqrtf(fmaxf(mdv.z, 1e-12f)));
    mx = fmaxf(mx,  sqrtf(fmaxf(mdv.w, 1e-12f)));
    mn =            (tjv.x != ti) ? sqrtf(fmaxf(idv.x, 1e-12f)) : INFINITY;
    mn = fminf(mn,  (tjv.y != ti) ? sqrtf(fmaxf(idv.y, 1e-12f)) : INFINITY);
    mn = fminf(mn,  (tjv.z != ti) ? sqrtf(fmaxf(idv.z, 1e-12f)) : INFINITY);
    mn = fminf(mn,  (tjv.w != ti) ? sqrtf(fmaxf(idv.w, 1e-12f)) : INFINITY);

    #pragma unroll
    for (int off = 32; off > 0; off >>= 1) {
        mx = fmaxf(mx, __shfl_xor(mx, off, 64));
        mn = fminf(mn, __shfl_xor(mn, off, 64));
    }
    if (lane == 0) {
        const float per = fmaxf(mx * 10.f - mn, 0.f);
        atomicAdd(acc, per * (1.0f / BB));
        __threadfence();
        const unsigned int old = atomicAdd(cnt_g, 1u);
        if (old == BB - 1) {
            __threadfence();
            out[0] = atomicAdd(acc, 0.0f);
        }
    }
}

extern "C" void kernel_launch(void* const* d_in, const int* in_sizes, int n_in,
                              void* d_out, int out_size, void* d_ws, size_t ws_size,
                              hipStream_t stream)
{
    const float* x       = (const float*)d_in[0];
    const int*   targets = (const int*)d_in[1];
    const int*   subs    = (const int*)d_in[2];
    const int*   m_count = (const int*)d_in[3];
    float* out  = (float*)d_out;

    float* mcsq = (float*)d_ws;                   // 256*1024
    float* S    = mcsq + (long)BB * CC;           // 256*256
    float* IDS  = S    + BB * BB;                 // 256*256
    float* MD   = IDS  + BB * BB;                 // 256*256
    float* acc  = MD   + BB * BB;                 // 1
    unsigned int* cnt_g = (unsigned int*)(acc + 1);

    mcsq_kernel <<<BB,   64,  0, stream>>>(x, targets, subs, m_count, mcsq, S, acc, cnt_g);
    pass1_kernel<<<512,  256, 0, stream>>>(x, S);
    pass2_kernel<<<1024, 256, 0, stream>>>(x, mcsq, S, IDS, MD);
    final_kernel<<<BB,   64,  0, stream>>>(IDS, MD, targets, acc, cnt_g, out);
}

// Round 7
// 99.328 us; speedup vs baseline: 1.0048x; 1.0048x over previous
//
#include <hip/hip_runtime.h>
#include <math.h>

#define BB 256       // batch
#define CC 1024      // channels
#define CC4 (CC/4)   // row length in float4
#define MARGIN 0.5f
#define NSL 8        // c-slices (chunks of 128)
#define LDST 132     // LDS row stride in floats (16B-aligned, odd float4 stride)

// ws (floats): mcsq[256*1024] | S_part[8*65536] | THR[65536] |
//              IDS_part[8*65536] | MD_part[8*65536] | acc | cnt

// ---------------------------------------------------------------------------
// K1: mcsq[i,c] = m_counts[i,c]^2. One wave per row; ballot partner select.
// ---------------------------------------------------------------------------
__global__ __launch_bounds__(64) void mcsq_kernel(
    const float* __restrict__ x, const int* __restrict__ targets,
    const int* __restrict__ subs, const int* __restrict__ m_count_p,
    float* __restrict__ mcsq, float* __restrict__ acc,
    unsigned int* __restrict__ cnt_g)
{
    const int i = blockIdx.x;
    const int lane = threadIdx.x;
    if (i == 0 && lane == 0) { *acc = 0.f; *cnt_g = 0u; }
    const int ti = targets[i], si = subs[i];
    int mc = *m_count_p;
    if (mc > 8) mc = 8;

    unsigned long long masks[4];
    #pragma unroll
    for (int q = 0; q < 4; ++q) {
        const int j = q * 64 + lane;
        masks[q] = __ballot(targets[j] == ti && subs[j] == si);
    }
    int idx[8];
    int cnt = 0;
    for (int q = 0; q < 4 && cnt < mc; ++q) {
        unsigned long long m = masks[q];
        while (m && cnt < mc) {
            const int b = __ffsll(m) - 1;
            idx[cnt++] = q * 64 + b;
            m &= m - 1;
        }
    }
    for (int q = 0; q < 4 && cnt < mc; ++q) {   // stable-argsort padding
        unsigned long long m = ~masks[q];
        while (m && cnt < mc) {
            const int b = __ffsll(m) - 1;
            idx[cnt++] = q * 64 + b;
            m &= m - 1;
        }
    }

    const float4* x4 = (const float4*)x;
    float4 xi[4];
    #pragma unroll
    for (int t = 0; t < 4; ++t) xi[t] = x4[(long)i * CC4 + lane + 64 * t];

    float4 c4[4];
    #pragma unroll
    for (int t = 0; t < 4; ++t) c4[t] = make_float4(0.f, 0.f, 0.f, 0.f);

    for (int k = 0; k < cnt; ++k) {
        float4 ad[4];
        float s = 0.f;
        #pragma unroll
        for (int t = 0; t < 4; ++t) {
            const float4 xj = x4[(long)idx[k] * CC4 + lane + 64 * t];
            ad[t].x = fabsf(xi[t].x - xj.x);
            ad[t].y = fabsf(xi[t].y - xj.y);
            ad[t].z = fabsf(xi[t].z - xj.z);
            ad[t].w = fabsf(xi[t].w - xj.w);
            s += ad[t].x + ad[t].y + ad[t].z + ad[t].w;
        }
        #pragma unroll
        for (int off = 32; off > 0; off >>= 1) s += __shfl_xor(s, off, 64);
        const float thr = s * (MARGIN / CC);
        #pragma unroll
        for (int t = 0; t < 4; ++t) {
            c4[t].x += (ad[t].x < thr) ? 1.f : 0.f;
            c4[t].y += (ad[t].y < thr) ? 1.f : 0.f;
            c4[t].z += (ad[t].z < thr) ? 1.f : 0.f;
            c4[t].w += (ad[t].w < thr) ? 1.f : 0.f;
        }
    }
    float4* m4 = (float4*)mcsq;
    #pragma unroll
    for (int t = 0; t < 4; ++t) {
        float4 o;
        o.x = c4[t].x * c4[t].x;
        o.y = c4[t].y * c4[t].y;
        o.z = c4[t].z * c4[t].z;
        o.w = c4[t].w * c4[t].w;
        m4[(long)i * CC4 + lane + 64 * t] = o;
    }
}

// ---------------------------------------------------------------------------
// K2 (pass1): partial L1 sums. Block = 32i x 32j x 128c; 2x2 pairs/lane;
// float4 LDS reads (stride 132 -> 16B aligned); NO atomics: each c-chunk
// writes its own slice S_part[cc][i][j]. Grid 8it*8jt*8cc = 512.
// ---------------------------------------------------------------------------
__global__ __launch_bounds__(256) void pass1_kernel(
    const float* __restrict__ x, float* __restrict__ S_part)
{
    __shared__ float xs[64 * LDST];
    const int b  = blockIdx.x;
    const int cc = b & 7;
    const int jt = (b >> 3) & 7;
    const int it = b >> 6;
    const int l  = threadIdx.x;

    const float4* x4 = (const float4*)x;
    #pragma unroll
    for (int k = 0; k < 8; ++k) {
        const int idx = l + 256 * k;       // 0..2047
        const int row = idx >> 5;          // 0..63
        const int c4  = idx & 31;
        const int grow = (row < 32) ? (it * 32 + row) : (jt * 32 + row - 32);
        *(float4*)&xs[row * LDST + c4 * 4] = x4[grow * CC4 + cc * 32 + c4];
    }
    __syncthreads();

    const int li = l >> 4, lj = l & 15;
    const float4* pi0 = (const float4*)&xs[(2 * li) * LDST];
    const float4* pi1 = (const float4*)&xs[(2 * li + 1) * LDST];
    const float4* pj0 = (const float4*)&xs[(32 + 2 * lj) * LDST];
    const float4* pj1 = (const float4*)&xs[(32 + 2 * lj + 1) * LDST];
    float s00 = 0.f, s01 = 0.f, s10 = 0.f, s11 = 0.f;
    #pragma unroll 8
    for (int q = 0; q < 32; ++q) {
        const float4 a0 = pi0[q], a1 = pi1[q], b0 = pj0[q], b1 = pj1[q];
        s00 += fabsf(a0.x - b0.x) + fabsf(a0.y - b0.y) + fabsf(a0.z - b0.z) + fabsf(a0.w - b0.w);
        s01 += fabsf(a0.x - b1.x) + fabsf(a0.y - b1.y) + fabsf(a0.z - b1.z) + fabsf(a0.w - b1.w);
        s10 += fabsf(a1.x - b0.x) + fabsf(a1.y - b0.y) + fabsf(a1.z - b0.z) + fabsf(a1.w - b0.w);
        s11 += fabsf(a1.x - b1.x) + fabsf(a1.y - b1.y) + fabsf(a1.z - b1.z) + fabsf(a1.w - b1.w);
    }
    const int gi0 = it * 32 + 2 * li, gj0 = jt * 32 + 2 * lj;
    float* Sp = S_part + cc * (BB * BB);
    Sp[gi0 * BB + gj0]           = s00;
    Sp[gi0 * BB + gj0 + 1]       = s01;
    Sp[(gi0 + 1) * BB + gj0]     = s10;
    Sp[(gi0 + 1) * BB + gj0 + 1] = s11;
}

// ---------------------------------------------------------------------------
// K3: THR[i][j] = (sum_cc S_part[cc][i][j]) * MARGIN/CC. Coalesced.
// ---------------------------------------------------------------------------
__global__ __launch_bounds__(256) void thr_kernel(
    const float* __restrict__ S_part, float* __restrict__ THR)
{
    const int g = blockIdx.x * 256 + threadIdx.x;   // 0..65535
    float s = 0.f;
    #pragma unroll
    for (int cc = 0; cc < NSL; ++cc) s += S_part[cc * (BB * BB) + g];
    THR[g] = s * (MARGIN / CC);
}

// ---------------------------------------------------------------------------
// K4 (pass2): partial IDS/MD sums. Same tiling as pass1; stages x AND mcsq;
// per-lane thresholds read from THR; slice outputs, NO atomics.
// ---------------------------------------------------------------------------
__global__ __launch_bounds__(256) void pass2_kernel(
    const float* __restrict__ x, const float* __restrict__ mcsq,
    const float* __restrict__ THR,
    float* __restrict__ IDS_part, float* __restrict__ MD_part)
{
    __shared__ float xs[64 * LDST];
    __shared__ float ms[64 * LDST];
    const int b  = blockIdx.x;
    const int cc = b & 7;
    const int jt = (b >> 3) & 7;
    const int it = b >> 6;
    const int l  = threadIdx.x;

    const float4* x4 = (const float4*)x;
    const float4* m4 = (const float4*)mcsq;
    #pragma unroll
    for (int k = 0; k < 8; ++k) {
        const int idx = l + 256 * k;
        const int row = idx >> 5;
        const int c4  = idx & 31;
        const int grow = (row < 32) ? (it * 32 + row) : (jt * 32 + row - 32);
        *(float4*)&xs[row * LDST + c4 * 4] = x4[grow * CC4 + cc * 32 + c4];
        *(float4*)&ms[row * LDST + c4 * 4] = m4[grow * CC4 + cc * 32 + c4];
    }
    const int li = l >> 4, lj = l & 15;
    const int gi0 = it * 32 + 2 * li, gj0 = jt * 32 + 2 * lj;
    const float t00 = THR[gi0 * BB + gj0];
    const float t01 = THR[gi0 * BB + gj0 + 1];
    const float t10 = THR[(gi0 + 1) * BB + gj0];
    const float t11 = THR[(gi0 + 1) * BB + gj0 + 1];
    __syncthreads();

    const float4* pi0 = (const float4*)&xs[(2 * li) * LDST];
    const float4* pi1 = (const float4*)&xs[(2 * li + 1) * LDST];
    const float4* pj0 = (const float4*)&xs[(32 + 2 * lj) * LDST];
    const float4* pj1 = (const float4*)&xs[(32 + 2 * lj + 1) * LDST];
    const float4* qi0 = (const float4*)&ms[(2 * li) * LDST];
    const float4* qi1 = (const float4*)&ms[(2 * li + 1) * LDST];
    const float4* qj0 = (const float4*)&ms[(32 + 2 * lj) * LDST];
    const float4* qj1 = (const float4*)&ms[(32 + 2 * lj + 1) * LDST];

    float i00 = 0.f, i01 = 0.f, i10 = 0.f, i11 = 0.f;
    float m00 = 0.f, m01 = 0.f, m10 = 0.f, m11 = 0.f;
    #pragma unroll 4
    for (int q = 0; q < 32; ++q) {
        const float4 a0 = pi0[q], a1 = pi1[q], b0 = pj0[q], b1 = pj1[q];
        const float4 wa0 = qi0[q], wa1 = qi1[q], wb0 = qj0[q], wb1 = qj1[q];
        #pragma unroll
        for (int u = 0; u < 4; ++u) {
            const float xa0 = (&a0.x)[u], xa1 = (&a1.x)[u];
            const float xb0 = (&b0.x)[u], xb1 = (&b1.x)[u];
            const float va0 = (&wa0.x)[u], va1 = (&wa1.x)[u];
            const float vb0 = (&wb0.x)[u], vb1 = (&wb1.x)[u];
            float d, qq;
            d = xa0 - xb0; qq = d * d; i00 += (fabsf(d) < t00) ? qq : 0.f; m00 += qq * va0 * vb0;
            d = xa0 - xb1; qq = d * d; i01 += (fabsf(d) < t01) ? qq : 0.f; m01 += qq * va0 * vb1;
            d = xa1 - xb0; qq = d * d; i10 += (fabsf(d) < t10) ? qq : 0.f; m10 += qq * va1 * vb0;
            d = xa1 - xb1; qq = d * d; i11 += (fabsf(d) < t11) ? qq : 0.f; m11 += qq * va1 * vb1;
        }
    }
    float* Ip = IDS_part + cc * (BB * BB);
    float* Mp = MD_part  + cc * (BB * BB);
    Ip[gi0 * BB + gj0]           = i00;
    Ip[gi0 * BB + gj0 + 1]       = i01;
    Ip[(gi0 + 1) * BB + gj0]     = i10;
    Ip[(gi0 + 1) * BB + gj0 + 1] = i11;
    Mp[gi0 * BB + gj0]           = m00;
    Mp[gi0 * BB + gj0 + 1]       = m01;
    Mp[(gi0 + 1) * BB + gj0]     = m10;
    Mp[(gi0 + 1) * BB + gj0 + 1] = m11;
}

// ---------------------------------------------------------------------------
// K5: final. One wave per row i: lane sums 8 slices for its 4 j's (float4),
// sqrt/max/min, one butterfly, atomic mean; last block publishes.
// ---------------------------------------------------------------------------
__global__ __launch_bounds__(64) void final_kernel(
    const float* __restrict__ IDS_part, const float* __restrict__ MD_part,
    const int* __restrict__ targets,
    float* __restrict__ acc, unsigned int* __restrict__ cnt_g,
    float* __restrict__ out)
{
    const int i = blockIdx.x;
    const int lane = threadIdx.x;
    const int ti = targets[i];

    float4 idv = make_float4(0.f, 0.f, 0.f, 0.f);
    float4 mdv = make_float4(0.f, 0.f, 0.f, 0.f);
    #pragma unroll
    for (int cc = 0; cc < NSL; ++cc) {
        const float4 a = ((const float4*)(IDS_part + cc * (BB * BB) + i * BB))[lane];
        const float4 b = ((const float4*)(MD_part  + cc * (BB * BB) + i * BB))[lane];
        idv.x += a.x; idv.y += a.y; idv.z += a.z; idv.w += a.w;
        mdv.x += b.x; mdv.y += b.y; mdv.z += b.z; mdv.w += b.w;
    }
    const int4 tjv = ((const int4*)targets)[lane];

    float mx, mn;
    mx =           sqrtf(fmaxf(mdv.x, 1e-12f));
    mx = fmaxf(mx, sqrtf(fmaxf(mdv.y, 1e-12f)));
    mx = fmaxf(mx, sqrtf(fmaxf(mdv.z, 1e-12f)));
    mx = fmaxf(mx, sqrtf(fmaxf(mdv.w, 1e-12f)));
    mn =           (tjv.x != ti) ? sqrtf(fmaxf(idv.x, 1e-12f)) : INFINITY;
    mn = fminf(mn, (tjv.y != ti) ? sqrtf(fmaxf(idv.y, 1e-12f)) : INFINITY);
    mn = fminf(mn, (tjv.z != ti) ? sqrtf(fmaxf(idv.z, 1e-12f)) : INFINITY);
    mn = fminf(mn, (tjv.w != ti) ? sqrtf(fmaxf(idv.w, 1e-12f)) : INFINITY);

    #pragma unroll
    for (int off = 32; off > 0; off >>= 1) {
        mx = fmaxf(mx, __shfl_xor(mx, off, 64));
        mn = fminf(mn, __shfl_xor(mn, off, 64));
    }
    if (lane == 0) {
        const float per = fmaxf(mx * 10.f - mn, 0.f);
        atomicAdd(acc, per * (1.0f / BB));
        __threadfence();
        const unsigned int old = atomicAdd(cnt_g, 1u);
        if (old == BB - 1) {
            __threadfence();
            out[0] = atomicAdd(acc, 0.0f);
        }
    }
}

extern "C" void kernel_launch(void* const* d_in, const int* in_sizes, int n_in,
                              void* d_out, int out_size, void* d_ws, size_t ws_size,
                              hipStream_t stream)
{
    const float* x       = (const float*)d_in[0];
    const int*   targets = (const int*)d_in[1];
    const int*   subs    = (const int*)d_in[2];
    const int*   m_count = (const int*)d_in[3];
    float* out  = (float*)d_out;

    float* mcsq     = (float*)d_ws;                    // 256*1024
    float* S_part   = mcsq     + (long)BB * CC;        // 8*65536
    float* THR      = S_part   + NSL * BB * BB;        // 65536
    float* IDS_part = THR      + BB * BB;              // 8*65536
    float* MD_part  = IDS_part + NSL * BB * BB;        // 8*65536
    float* acc      = MD_part  + NSL * BB * BB;        // 1
    unsigned int* cnt_g = (unsigned int*)(acc + 1);

    mcsq_kernel <<<BB,  64,  0, stream>>>(x, targets, subs, m_count, mcsq, acc, cnt_g);
    pass1_kernel<<<512, 256, 0, stream>>>(x, S_part);
    thr_kernel  <<<256, 256, 0, stream>>>(S_part, THR);
    pass2_kernel<<<512, 256, 0, stream>>>(x, mcsq, THR, IDS_part, MD_part);
    final_kernel<<<BB,  64,  0, stream>>>(IDS_part, MD_part, targets, acc, cnt_g, out);
}